// Round 19
// baseline (192.543 us; speedup 1.0000x reference)
//
#include <hip/hip_runtime.h>
#include <stdint.h>

#define DI __device__ __forceinline__

typedef __attribute__((ext_vector_type(8))) short bf16x8;
typedef __attribute__((ext_vector_type(4))) float f32x4;
typedef __attribute__((ext_vector_type(8))) unsigned short u16x8;
typedef __attribute__((ext_vector_type(2))) unsigned int u32x2;
typedef __attribute__((ext_vector_type(4))) unsigned int u32x4;

static constexpr int BATCH = 4, SEQ = 2048, DIM = 1024, NH = 16, HDIM = 64, DOUT = 256;
static constexpr int MROWS = BATCH * SEQ;  // 8192

DI unsigned short f2b(float f) {
  union { float f; unsigned u; } v; v.f = f;
  unsigned u = v.u + 0x7FFFu + ((v.u >> 16) & 1u);
  return (unsigned short)(u >> 16);
}

DI float ex2(float x) {  // 2^x, single v_exp_f32
#if __has_builtin(__builtin_amdgcn_exp2f)
  return __builtin_amdgcn_exp2f(x);
#else
  float r; asm("v_exp_f32 %0, %1" : "=v"(r) : "v"(x)); return r;
#endif
}

DI unsigned cvtpk(float lo, float hi) {  // packed bf16(lo) | bf16(hi)<<16, RNE
  unsigned r; asm("v_cvt_pk_bf16_f32 %0, %1, %2" : "=v"(r) : "v"(lo), "v"(hi)); return r;
}

typedef const __attribute__((address_space(1))) unsigned int* gp1;
typedef __attribute__((address_space(3))) unsigned int* lp3;
DI void gload16(const void* g, void* l) {
  __builtin_amdgcn_global_load_lds((gp1)g, (lp3)l, 16, 0, 0);
}

// ---------------- f32 [R][C] -> bf16 [C][R] transpose-convert (z-batched) ----------------
__global__ void k_tcvt3(const float* __restrict__ s0, const float* __restrict__ s1,
                        const float* __restrict__ s2, unsigned short* __restrict__ d, int R, int C) {
  __shared__ float t[32][33];
  const float* s = (blockIdx.z == 0) ? s0 : (blockIdx.z == 1) ? s1 : s2;
  unsigned short* dz = d + (size_t)blockIdx.z * R * C;
  int c0 = blockIdx.x * 32, r0 = blockIdx.y * 32;
  int tx = threadIdx.x, ty = threadIdx.y;  // block (32,8)
#pragma unroll
  for (int j = 0; j < 32; j += 8)
    t[ty + j][tx] = s[(size_t)(r0 + ty + j) * C + c0 + tx];
  __syncthreads();
#pragma unroll
  for (int j = 0; j < 32; j += 8)
    dz[(size_t)(c0 + ty + j) * R + r0 + tx] = f2b(t[tx][ty + j]);
}

__global__ void k_tcvt(const float* __restrict__ s, unsigned short* __restrict__ d, int R, int C) {
  __shared__ float t[32][33];
  int c0 = blockIdx.x * 32, r0 = blockIdx.y * 32;
  int tx = threadIdx.x, ty = threadIdx.y;  // block (32,8)
#pragma unroll
  for (int j = 0; j < 32; j += 8)
    t[ty + j][tx] = s[(size_t)(r0 + ty + j) * C + c0 + tx];
  __syncthreads();
#pragma unroll
  for (int j = 0; j < 32; j += 8)
    d[(size_t)(c0 + ty + j) * R + r0 + tx] = f2b(t[tx][ty + j]);
}

// ---------------- fused QKV projection: 3 GEMMs in one launch (z = 0:Q 1:K 2:V) ----------
// A f32 staged to LDS bf16 via reg loads + cvt_pk.
// r19: DOUBLE-BUFFERED B. r18 showed the per-iter stall is B's gload16 issued
// immediately before the RAW __syncthreads (vmcnt(0) drain -> full L2/HBM latency
// exposed each K-iter; MfmaUtil 17%, VALU 13%, HBM 9% = all idle). Now B(t+1) is
// issued right AFTER the RAW barrier (A reg-prefetch first, so ar's wait is a
// counted vmcnt leaving B in flight); the next iter's RAW barrier drains it after
// a full iteration of slack. Bottom WAR barrier stays raw s_barrier (no drain).
__global__ __launch_bounds__(256, 2) void k_gemm3(
    const float* __restrict__ Aq, const float* __restrict__ Ak, const float* __restrict__ Av,
    const unsigned short* __restrict__ Wt3,
    const float* __restrict__ bq, const float* __restrict__ bk, const float* __restrict__ bv,
    unsigned short* __restrict__ Qh, unsigned short* __restrict__ Kh,
    unsigned short* __restrict__ Vtb, float qscale) {
  __shared__ unsigned short Al[128 * 32];
  __shared__ unsigned short Bl[2][128 * 32];
  const int tid = threadIdx.x, wid = tid >> 6, lane = tid & 63;
  const int m0 = blockIdx.x * 128, n0 = blockIdx.y * 128;
  const int z = blockIdx.z;
  const int wr = wid >> 1, wc = wid & 1;
  const int g = lane >> 4, r16 = lane & 15;
  const int K = DIM;

  const float* Af = (z == 0) ? Aq : (z == 1) ? Ak : Av;
  const unsigned short* Bt = Wt3 + (size_t)z * DIM * DIM;
  const float* bias = (z == 0) ? bq : (z == 1) ? bk : bv;
  const float scale = (z == 0) ? qscale : 1.0f;

  // reg-staging geometry: slot f8 = j*256+tid -> row = f8>>2, col8 = (f8&3)*8
  const int ra = tid >> 2, ca = (tid & 3) * 8;
  const int rb = (256 + tid) >> 2, cb = ((256 + tid) & 3) * 8;
  // B staging slots (gload16): slot = (is*4+wid)*64+lane
  const int bslot0 = wid * 64 + lane, bslot1 = (4 + wid) * 64 + lane;
  const int br0 = bslot0 >> 2, bc0 = (bslot0 & 3) * 8;
  const int br1 = bslot1 >> 2, bc1 = (bslot1 & 3) * 8;
  const int bld0 = wid * 512, bld1 = (4 + wid) * 512;

  float4 ar[2][2];
  {
    const float4* pa = reinterpret_cast<const float4*>(Af + (size_t)(m0 + ra) * K + ca);
    const float4* pb = reinterpret_cast<const float4*>(Af + (size_t)(m0 + rb) * K + cb);
    ar[0][0] = pa[0]; ar[0][1] = pa[1];
    ar[1][0] = pb[0]; ar[1][1] = pb[1];
  }
  // prologue: B(0) into Bl[0] (issued after A(0) reg loads -> A wait is counted)
  gload16(Bt + (size_t)(n0 + br0) * K + bc0, &Bl[0][bld0]);
  gload16(Bt + (size_t)(n0 + br1) * K + bc1, &Bl[0][bld1]);

  f32x4 acc[4][4];
#pragma unroll
  for (int i = 0; i < 4; ++i)
#pragma unroll
    for (int j = 0; j < 4; ++j) acc[i][j] = f32x4{0.f, 0.f, 0.f, 0.f};

  int cur = 0;
  for (int kk = 0; kk < K; kk += 32) {
    // stage A(t) from regs (compiler waits counted vmcnt for ar; B stays in flight)
    u32x4 w0{cvtpk(ar[0][0].x, ar[0][0].y), cvtpk(ar[0][0].z, ar[0][0].w),
             cvtpk(ar[0][1].x, ar[0][1].y), cvtpk(ar[0][1].z, ar[0][1].w)};
    *reinterpret_cast<u32x4*>(&Al[ra * 32 + ca]) = w0;
    u32x4 w1{cvtpk(ar[1][0].x, ar[1][0].y), cvtpk(ar[1][0].z, ar[1][0].w),
             cvtpk(ar[1][1].x, ar[1][1].y), cvtpk(ar[1][1].z, ar[1][1].w)};
    *reinterpret_cast<u32x4*>(&Al[rb * 32 + cb]) = w1;
    __syncthreads();  // RAW: A(t) ds_writes + B(t) gloads (in flight since t-1) visible
    if (kk + 32 < K) {
      // A(t+1) reg loads FIRST (oldest in vmcnt queue -> counted wait at next use)
      const float4* pa = reinterpret_cast<const float4*>(Af + (size_t)(m0 + ra) * K + kk + 32 + ca);
      const float4* pb = reinterpret_cast<const float4*>(Af + (size_t)(m0 + rb) * K + kk + 32 + cb);
      ar[0][0] = pa[0]; ar[0][1] = pa[1];
      ar[1][0] = pb[0]; ar[1][1] = pb[1];
      // B(t+1) SECOND -> in flight across the whole MFMA phase + next A-stage
      gload16(Bt + (size_t)(n0 + br0) * K + kk + 32 + bc0, &Bl[cur ^ 1][bld0]);
      gload16(Bt + (size_t)(n0 + br1) * K + kk + 32 + bc1, &Bl[cur ^ 1][bld1]);
    }
    bf16x8 af[4], bfv[4];
#pragma unroll
    for (int i = 0; i < 4; ++i)
      af[i] = *reinterpret_cast<const bf16x8*>(&Al[(wr * 64 + i * 16 + r16) * 32 + g * 8]);
#pragma unroll
    for (int j = 0; j < 4; ++j)
      bfv[j] = *reinterpret_cast<const bf16x8*>(&Bl[cur][(wc * 64 + j * 16 + r16) * 32 + g * 8]);
#pragma unroll
    for (int i = 0; i < 4; ++i)
#pragma unroll
      for (int j = 0; j < 4; ++j)
        acc[i][j] = __builtin_amdgcn_mfma_f32_16x16x32_bf16(af[i], bfv[j], acc[i][j], 0, 0, 0);
    asm volatile("s_barrier" ::: "memory");  // WAR on Al (raw, no drain); Bl safe via dbuf
    cur ^= 1;
  }

  const int rr = g * 4;
#pragma unroll
  for (int i = 0; i < 4; ++i) {
#pragma unroll
    for (int j = 0; j < 4; ++j) {
#pragma unroll
      for (int q = 0; q < 4; ++q) {
        int mrow = m0 + wr * 64 + i * 16 + rr + q;
        int ncol = n0 + wc * 64 + j * 16 + r16;
        float v = (acc[i][j][q] + bias[ncol]) * scale;
        int b_ = mrow >> 11, s_ = mrow & 2047;
        int h_ = ncol >> 6, hd = ncol & 63;
        if (z == 2) {
          Vtb[(((size_t)(b_ * NH + h_) * HDIM + hd) << 11) + s_] = f2b(v);
        } else {
          unsigned short* dst = (z == 0) ? Qh : Kh;
          dst[(((size_t)(b_ * NH + h_) * SEQ + s_) << 6) + hd] = f2b(v);
        }
      }
    }
  }
}

// ---------------- final projection: A bf16 [M,K] x Wt [N,K]^T -> f32 [M,N] ----------------
__global__ __launch_bounds__(256, 2) void k_gemmf(
    const unsigned short* __restrict__ A, const unsigned short* __restrict__ Bt,
    const float* __restrict__ bias, float* __restrict__ out, int K, int N) {
  __shared__ unsigned short Al[128 * 32];
  __shared__ unsigned short Bl[128 * 32];
  const int tid = threadIdx.x, wid = tid >> 6, lane = tid & 63;
  const int m0 = blockIdx.x * 128, n0 = blockIdx.y * 128;
  const int wr = wid >> 1, wc = wid & 1;
  const int g = lane >> 4, r16 = lane & 15;

  f32x4 acc[4][4];
#pragma unroll
  for (int i = 0; i < 4; ++i)
#pragma unroll
    for (int j = 0; j < 4; ++j) acc[i][j] = f32x4{0.f, 0.f, 0.f, 0.f};

  for (int kk = 0; kk < K; kk += 32) {
#pragma unroll
    for (int is = 0; is < 2; ++is) {
      int slot = (is * 4 + wid) * 64 + lane;
      int row = slot >> 2, ch = slot & 3;
      gload16(A + (size_t)(m0 + row) * K + kk + ch * 8, &Al[(is * 4 + wid) * 64 * 8]);
    }
#pragma unroll
    for (int is = 0; is < 2; ++is) {
      int slot = (is * 4 + wid) * 64 + lane;
      int row = slot >> 2, ch = slot & 3;
      gload16(Bt + (size_t)(n0 + row) * K + kk + ch * 8, &Bl[(is * 4 + wid) * 64 * 8]);
    }
    __syncthreads();
    bf16x8 af[4], bfv[4];
#pragma unroll
    for (int i = 0; i < 4; ++i)
      af[i] = *reinterpret_cast<const bf16x8*>(&Al[(wr * 64 + i * 16 + r16) * 32 + g * 8]);
#pragma unroll
    for (int j = 0; j < 4; ++j)
      bfv[j] = *reinterpret_cast<const bf16x8*>(&Bl[(wc * 64 + j * 16 + r16) * 32 + g * 8]);
#pragma unroll
    for (int i = 0; i < 4; ++i)
#pragma unroll
      for (int j = 0; j < 4; ++j)
        acc[i][j] = __builtin_amdgcn_mfma_f32_16x16x32_bf16(af[i], bfv[j], acc[i][j], 0, 0, 0);
    __syncthreads();
  }

  const int rr = g * 4;
#pragma unroll
  for (int i = 0; i < 4; ++i)
#pragma unroll
    for (int j = 0; j < 4; ++j)
#pragma unroll
      for (int q = 0; q < 4; ++q) {
        int mrow = m0 + wr * 64 + i * 16 + rr + q;
        int ncol = n0 + wc * 64 + j * 16 + r16;
        out[(size_t)mrow * N + ncol] = acc[i][j][q] + bias[ncol];
      }
}

// ---------------- attention with "+1" sink softmax, NO max subtraction ----------------
// (r14-verified: swapped QK^T, exp2 domain, cvt_pk P-pack, ones-column row sums,
//  single-buffer 32KB LDS, launch_bounds(256,4))
__global__ __launch_bounds__(256, 4) void k_attn(
    const unsigned short* __restrict__ Qh, const unsigned short* __restrict__ Kh,
    const unsigned short* __restrict__ Vt, unsigned short* __restrict__ X) {
  __shared__ unsigned short Kl[64 * 64];   // [kv][hd], chunk-swizzled
  __shared__ unsigned short Vl[64 * 64];   // [hd][kv], chunk-swizzled
  __shared__ unsigned short Pl[128 * 64];  // [q][kv],  chunk-swizzled (wave-private rows)

  const int tid = threadIdx.x, wid = tid >> 6, lane = tid & 63;
  const int g = lane >> 4, r16 = lane & 15;
  const int bh = blockIdx.y, b_ = bh >> 4, h_ = bh & 15;
  const int q0 = blockIdx.x * 128;
  const unsigned short* Qp = Qh + ((size_t)bh * SEQ + q0) * HDIM;
  const unsigned short* Kp = Kh + (size_t)bh * SEQ * HDIM;
  const unsigned short* Vp = Vt + (size_t)bh * HDIM * SEQ;
  const int qw = wid * 32;

  bf16x8 qf[2][2];
#pragma unroll
  for (int fr = 0; fr < 2; ++fr)
#pragma unroll
    for (int ks = 0; ks < 2; ++ks)
      qf[fr][ks] = *reinterpret_cast<const bf16x8*>(
          Qp + (size_t)(qw + fr * 16 + r16) * HDIM + ks * 32 + g * 8);

  bf16x8 vones;
#pragma unroll
  for (int i = 0; i < 8; ++i) vones[i] = (r16 == 0) ? (short)0x3F80 : (short)0;

  const int slot0 = wid * 64 + lane, slot1 = (4 + wid) * 64 + lane;
  const int sr0 = slot0 >> 3, sc0 = (slot0 & 7) ^ (sr0 & 7);
  const int sr1 = slot1 >> 3, sc1 = (slot1 & 7) ^ (sr1 & 7);
  const unsigned short* Ks0 = Kp + (size_t)sr0 * HDIM + sc0 * 8;
  const unsigned short* Ks1 = Kp + (size_t)sr1 * HDIM + sc1 * 8;
  const unsigned short* Vs0 = Vp + (size_t)sr0 * SEQ + sc0 * 8;
  const unsigned short* Vs1 = Vp + (size_t)sr1 * SEQ + sc1 * 8;
  const int ld0 = wid * 512, ld1 = (4 + wid) * 512;

  f32x4 o[2][4], ol[2];
#pragma unroll
  for (int fr = 0; fr < 2; ++fr) {
#pragma unroll
    for (int hf = 0; hf < 4; ++hf) o[fr][hf] = f32x4{0.f, 0.f, 0.f, 0.f};
    ol[fr] = f32x4{0.f, 0.f, 0.f, 0.f};
  }

  for (int t = 0; t < SEQ / 64; ++t) {
    __syncthreads();  // WAR
    {
      const size_t koff = (size_t)t * 64 * HDIM;
      const int voff = t * 64;
      gload16(Ks0 + koff, &Kl[ld0]);
      gload16(Ks1 + koff, &Kl[ld1]);
      gload16(Vs0 + voff, &Vl[ld0]);
      gload16(Vs1 + voff, &Vl[ld1]);
    }
    __syncthreads();  // RAW

    f32x4 s_[2][4];
#pragma unroll
    for (int fr = 0; fr < 2; ++fr)
#pragma unroll
      for (int cf = 0; cf < 4; ++cf) s_[fr][cf] = f32x4{0.f, 0.f, 0.f, 0.f};
#pragma unroll
    for (int cf = 0; cf < 4; ++cf) {
      int krow = cf * 16 + r16;
#pragma unroll
      for (int ks = 0; ks < 2; ++ks) {
        bf16x8 kf = *reinterpret_cast<const bf16x8*>(
            &Kl[krow * 64 + (((ks * 4 + g) ^ (krow & 7)) << 3)]);
#pragma unroll
        for (int fr = 0; fr < 2; ++fr)
          s_[fr][cf] = __builtin_amdgcn_mfma_f32_16x16x32_bf16(kf, qf[fr][ks], s_[fr][cf], 0, 0, 0);
      }
    }

#pragma unroll
    for (int fr = 0; fr < 2; ++fr) {
      int prow = qw + fr * 16 + r16;
      int base = prow * 64, swz = prow & 7;
#pragma unroll
      for (int cf = 0; cf < 4; ++cf) {
        float p0 = ex2(s_[fr][cf][0]);
        float p1 = ex2(s_[fr][cf][1]);
        float p2 = ex2(s_[fr][cf][2]);
        float p3 = ex2(s_[fr][cf][3]);
        unsigned w0 = cvtpk(p0, p1);
        unsigned w1 = cvtpk(p2, p3);
        int off = base + (((cf * 2 + (g >> 1)) ^ swz) << 3) + (g & 1) * 4;
        *reinterpret_cast<u32x2*>(&Pl[off]) = u32x2{w0, w1};
      }
    }

#pragma unroll
    for (int ks = 0; ks < 2; ++ks) {
      bf16x8 pf[2];
#pragma unroll
      for (int fr = 0; fr < 2; ++fr) {
        int prow = qw + fr * 16 + r16;
        pf[fr] = *reinterpret_cast<const bf16x8*>(
            &Pl[prow * 64 + (((ks * 4 + g) ^ (prow & 7)) << 3)]);
      }
#pragma unroll
      for (int hf = 0; hf < 4; ++hf) {
        int vrow = hf * 16 + r16;
        bf16x8 vf = *reinterpret_cast<const bf16x8*>(
            &Vl[vrow * 64 + (((ks * 4 + g) ^ (vrow & 7)) << 3)]);
#pragma unroll
        for (int fr = 0; fr < 2; ++fr)
          o[fr][hf] = __builtin_amdgcn_mfma_f32_16x16x32_bf16(pf[fr], vf, o[fr][hf], 0, 0, 0);
      }
#pragma unroll
      for (int fr = 0; fr < 2; ++fr)
        ol[fr] = __builtin_amdgcn_mfma_f32_16x16x32_bf16(pf[fr], vones, ol[fr], 0, 0, 0);
    }
  }

#pragma unroll
  for (int fr = 0; fr < 2; ++fr) {
#pragma unroll
    for (int q = 0; q < 4; ++q) {
      float lsum = __shfl(ol[fr][q], lane & 48, 64);
      float inv = 1.0f / (1.0f + lsum);
      int row = q0 + qw + fr * 16 + g * 4 + q;
      unsigned short* xp = X + (size_t)(b_ * SEQ + row) * DIM + h_ * 64;
#pragma unroll
      for (int hf = 0; hf < 4; ++hf) xp[hf * 16 + r16] = f2b(o[fr][hf][q] * inv);
    }
  }
}

extern "C" void kernel_launch(void* const* d_in, const int* in_sizes, int n_in,
                              void* d_out, int out_size, void* d_ws, size_t ws_size,
                              hipStream_t stream) {
  const float* q  = (const float*)d_in[0];
  const float* k  = (const float*)d_in[1];
  const float* v  = (const float*)d_in[2];
  const float* Wq = (const float*)d_in[3];
  const float* bq = (const float*)d_in[4];
  const float* Wk = (const float*)d_in[5];
  const float* bk = (const float*)d_in[6];
  const float* Wv = (const float*)d_in[7];
  const float* bv = (const float*)d_in[8];
  const float* Wf = (const float*)d_in[9];
  const float* bf = (const float*)d_in[10];

  char* ws = (char*)d_ws;
  unsigned short* Abuf = (unsigned short*)ws;                              // attn X (8192*1024 bf16)
  unsigned short* Wt3  = (unsigned short*)(ws + (size_t)16777216);         // 3 x 1024x1024 bf16
  unsigned short* Wtf  = Wt3 + (size_t)3 * DIM * DIM;                      // 256x1024 bf16
  unsigned short* Qh   = Wtf + (size_t)DOUT * DIM;
  unsigned short* Kh   = Qh + (size_t)MROWS * DIM;
  unsigned short* Vtb  = Kh + (size_t)MROWS * DIM;

  dim3 b256(256);
  dim3 tb(32, 8);

  const float qscale = 0.125f * 1.44269504088896f;  // 1/sqrt(64) * log2(e): S in log2 units

  // weights: 3 transposes in one launch; final-proj transpose separate
  k_tcvt3<<<dim3(32, 32, 3), tb, 0, stream>>>(Wq, Wk, Wv, Wt3, DIM, DIM);
  k_tcvt<<<dim3(8, 32), tb, 0, stream>>>(Wf, Wtf, DIM, DOUT);
  // fused QKV projection (1536 blocks, cross-GEMM overlap, B double-buffered)
  k_gemm3<<<dim3(64, 8, 3), b256, 0, stream>>>(q, k, v, Wt3, bq, bk, bv, Qh, Kh, Vtb, qscale);
  // attention -> X (Abuf)
  k_attn<<<dim3(16, 64), b256, 0, stream>>>(Qh, Kh, Vtb, Abuf);
  // final projection -> f32 out
  k_gemmf<<<dim3(64, 2), b256, 0, stream>>>(Abuf, Wtf, bf, (float*)d_out, DIM, DOUT);
}

// Round 25
// 189.114 us; speedup vs baseline: 1.0181x; 1.0181x over previous
//
#include <hip/hip_runtime.h>
#include <stdint.h>

#define DI __device__ __forceinline__

typedef __attribute__((ext_vector_type(8))) short bf16x8;
typedef __attribute__((ext_vector_type(4))) float f32x4;
typedef __attribute__((ext_vector_type(8))) unsigned short u16x8;
typedef __attribute__((ext_vector_type(2))) unsigned int u32x2;
typedef __attribute__((ext_vector_type(4))) unsigned int u32x4;

static constexpr int BATCH = 4, SEQ = 2048, DIM = 1024, NH = 16, HDIM = 64, DOUT = 256;
static constexpr int MROWS = BATCH * SEQ;  // 8192

DI unsigned short f2b(float f) {
  union { float f; unsigned u; } v; v.f = f;
  unsigned u = v.u + 0x7FFFu + ((v.u >> 16) & 1u);
  return (unsigned short)(u >> 16);
}

DI float ex2(float x) {  // 2^x, single v_exp_f32
#if __has_builtin(__builtin_amdgcn_exp2f)
  return __builtin_amdgcn_exp2f(x);
#else
  float r; asm("v_exp_f32 %0, %1" : "=v"(r) : "v"(x)); return r;
#endif
}

DI unsigned cvtpk(float lo, float hi) {  // packed bf16(lo) | bf16(hi)<<16, RNE
  unsigned r; asm("v_cvt_pk_bf16_f32 %0, %1, %2" : "=v"(r) : "v"(lo), "v"(hi)); return r;
}

typedef const __attribute__((address_space(1))) unsigned int* gp1;
typedef __attribute__((address_space(3))) unsigned int* lp3;
DI void gload16(const void* g, void* l) {
  __builtin_amdgcn_global_load_lds((gp1)g, (lp3)l, 16, 0, 0);
}

// ---------------- f32 [R][C] -> bf16 [C][R] transpose-convert (z-batched) ----------------
__global__ void k_tcvt3(const float* __restrict__ s0, const float* __restrict__ s1,
                        const float* __restrict__ s2, unsigned short* __restrict__ d, int R, int C) {
  __shared__ float t[32][33];
  const float* s = (blockIdx.z == 0) ? s0 : (blockIdx.z == 1) ? s1 : s2;
  unsigned short* dz = d + (size_t)blockIdx.z * R * C;
  int c0 = blockIdx.x * 32, r0 = blockIdx.y * 32;
  int tx = threadIdx.x, ty = threadIdx.y;  // block (32,8)
#pragma unroll
  for (int j = 0; j < 32; j += 8)
    t[ty + j][tx] = s[(size_t)(r0 + ty + j) * C + c0 + tx];
  __syncthreads();
#pragma unroll
  for (int j = 0; j < 32; j += 8)
    dz[(size_t)(c0 + ty + j) * R + r0 + tx] = f2b(t[tx][ty + j]);
}

__global__ void k_tcvt(const float* __restrict__ s, unsigned short* __restrict__ d, int R, int C) {
  __shared__ float t[32][33];
  int c0 = blockIdx.x * 32, r0 = blockIdx.y * 32;
  int tx = threadIdx.x, ty = threadIdx.y;  // block (32,8)
#pragma unroll
  for (int j = 0; j < 32; j += 8)
    t[ty + j][tx] = s[(size_t)(r0 + ty + j) * C + c0 + tx];
  __syncthreads();
#pragma unroll
  for (int j = 0; j < 32; j += 8)
    d[(size_t)(c0 + ty + j) * R + r0 + tx] = f2b(t[tx][ty + j]);
}

// ---------------- fused QKV projection: 3 GEMMs in one launch (z = 0:Q 1:K 2:V) ----------
// CONSERVATIVE (r25): both barriers are full __syncthreads. The raw s_barrier WAR
// (r17) was measured NEUTRAL (122.9 vs 122.5 us) but is a race suspect on the new
// container (r23/r24 both failed ~1.2e-2 with it); removing it costs ~nothing.
__global__ __launch_bounds__(256, 2) void k_gemm3(
    const float* __restrict__ Aq, const float* __restrict__ Ak, const float* __restrict__ Av,
    const unsigned short* __restrict__ Wt3,
    const float* __restrict__ bq, const float* __restrict__ bk, const float* __restrict__ bv,
    unsigned short* __restrict__ Qh, unsigned short* __restrict__ Kh,
    unsigned short* __restrict__ Vtb, float qscale) {
  __shared__ unsigned short Al[128 * 32];
  __shared__ unsigned short Bl[128 * 32];
  const int tid = threadIdx.x, wid = tid >> 6, lane = tid & 63;
  const int m0 = blockIdx.x * 128, n0 = blockIdx.y * 128;
  const int z = blockIdx.z;
  const int wr = wid >> 1, wc = wid & 1;
  const int g = lane >> 4, r16 = lane & 15;
  const int K = DIM;

  const float* Af = (z == 0) ? Aq : (z == 1) ? Ak : Av;
  const unsigned short* Bt = Wt3 + (size_t)z * DIM * DIM;
  const float* bias = (z == 0) ? bq : (z == 1) ? bk : bv;
  const float scale = (z == 0) ? qscale : 1.0f;

  const int ra = tid >> 2, ca = (tid & 3) * 8;
  const int rb = (256 + tid) >> 2, cb = ((256 + tid) & 3) * 8;
  float4 ar[2][2];
  {
    const float4* pa = reinterpret_cast<const float4*>(Af + (size_t)(m0 + ra) * K + ca);
    const float4* pb = reinterpret_cast<const float4*>(Af + (size_t)(m0 + rb) * K + cb);
    ar[0][0] = pa[0]; ar[0][1] = pa[1];
    ar[1][0] = pb[0]; ar[1][1] = pb[1];
  }

  f32x4 acc[4][4];
#pragma unroll
  for (int i = 0; i < 4; ++i)
#pragma unroll
    for (int j = 0; j < 4; ++j) acc[i][j] = f32x4{0.f, 0.f, 0.f, 0.f};

  for (int kk = 0; kk < K; kk += 32) {
    u32x4 w0{cvtpk(ar[0][0].x, ar[0][0].y), cvtpk(ar[0][0].z, ar[0][0].w),
             cvtpk(ar[0][1].x, ar[0][1].y), cvtpk(ar[0][1].z, ar[0][1].w)};
    *reinterpret_cast<u32x4*>(&Al[ra * 32 + ca]) = w0;
    u32x4 w1{cvtpk(ar[1][0].x, ar[1][0].y), cvtpk(ar[1][0].z, ar[1][0].w),
             cvtpk(ar[1][1].x, ar[1][1].y), cvtpk(ar[1][1].z, ar[1][1].w)};
    *reinterpret_cast<u32x4*>(&Al[rb * 32 + cb]) = w1;
#pragma unroll
    for (int is = 0; is < 2; ++is) {
      int slot = (is * 4 + wid) * 64 + lane;
      int row = slot >> 2, ch = slot & 3;
      gload16(Bt + (size_t)(n0 + row) * K + kk + ch * 8, &Bl[(is * 4 + wid) * 64 * 8]);
    }
    __syncthreads();  // RAW: A ds_writes + B gloads visible
    if (kk + 32 < K) {
      const float4* pa = reinterpret_cast<const float4*>(Af + (size_t)(m0 + ra) * K + kk + 32 + ca);
      const float4* pb = reinterpret_cast<const float4*>(Af + (size_t)(m0 + rb) * K + kk + 32 + cb);
      ar[0][0] = pa[0]; ar[0][1] = pa[1];
      ar[1][0] = pb[0]; ar[1][1] = pb[1];
    }
    bf16x8 af[4], bfv[4];
#pragma unroll
    for (int i = 0; i < 4; ++i)
      af[i] = *reinterpret_cast<const bf16x8*>(&Al[(wr * 64 + i * 16 + r16) * 32 + g * 8]);
#pragma unroll
    for (int j = 0; j < 4; ++j)
      bfv[j] = *reinterpret_cast<const bf16x8*>(&Bl[(wc * 64 + j * 16 + r16) * 32 + g * 8]);
#pragma unroll
    for (int i = 0; i < 4; ++i)
#pragma unroll
      for (int j = 0; j < 4; ++j)
        acc[i][j] = __builtin_amdgcn_mfma_f32_16x16x32_bf16(af[i], bfv[j], acc[i][j], 0, 0, 0);
    __syncthreads();  // WAR: full barrier (conservative)
  }

  const int rr = g * 4;
#pragma unroll
  for (int i = 0; i < 4; ++i) {
#pragma unroll
    for (int j = 0; j < 4; ++j) {
#pragma unroll
      for (int q = 0; q < 4; ++q) {
        int mrow = m0 + wr * 64 + i * 16 + rr + q;
        int ncol = n0 + wc * 64 + j * 16 + r16;
        float v = (acc[i][j][q] + bias[ncol]) * scale;
        int b_ = mrow >> 11, s_ = mrow & 2047;
        int h_ = ncol >> 6, hd = ncol & 63;
        if (z == 2) {
          Vtb[(((size_t)(b_ * NH + h_) * HDIM + hd) << 11) + s_] = f2b(v);
        } else {
          unsigned short* dst = (z == 0) ? Qh : Kh;
          dst[(((size_t)(b_ * NH + h_) * SEQ + s_) << 6) + hd] = f2b(v);
        }
      }
    }
  }
}

// ---------------- final projection: A bf16 [M,K] x Wt [N,K]^T -> f32 [M,N] ----------------
__global__ __launch_bounds__(256, 2) void k_gemmf(
    const unsigned short* __restrict__ A, const unsigned short* __restrict__ Bt,
    const float* __restrict__ bias, float* __restrict__ out, int K, int N) {
  __shared__ unsigned short Al[128 * 32];
  __shared__ unsigned short Bl[128 * 32];
  const int tid = threadIdx.x, wid = tid >> 6, lane = tid & 63;
  const int m0 = blockIdx.x * 128, n0 = blockIdx.y * 128;
  const int wr = wid >> 1, wc = wid & 1;
  const int g = lane >> 4, r16 = lane & 15;

  f32x4 acc[4][4];
#pragma unroll
  for (int i = 0; i < 4; ++i)
#pragma unroll
    for (int j = 0; j < 4; ++j) acc[i][j] = f32x4{0.f, 0.f, 0.f, 0.f};

  for (int kk = 0; kk < K; kk += 32) {
#pragma unroll
    for (int is = 0; is < 2; ++is) {
      int slot = (is * 4 + wid) * 64 + lane;
      int row = slot >> 2, ch = slot & 3;
      gload16(A + (size_t)(m0 + row) * K + kk + ch * 8, &Al[(is * 4 + wid) * 64 * 8]);
    }
#pragma unroll
    for (int is = 0; is < 2; ++is) {
      int slot = (is * 4 + wid) * 64 + lane;
      int row = slot >> 2, ch = slot & 3;
      gload16(Bt + (size_t)(n0 + row) * K + kk + ch * 8, &Bl[(is * 4 + wid) * 64 * 8]);
    }
    __syncthreads();
    bf16x8 af[4], bfv[4];
#pragma unroll
    for (int i = 0; i < 4; ++i)
      af[i] = *reinterpret_cast<const bf16x8*>(&Al[(wr * 64 + i * 16 + r16) * 32 + g * 8]);
#pragma unroll
    for (int j = 0; j < 4; ++j)
      bfv[j] = *reinterpret_cast<const bf16x8*>(&Bl[(wc * 64 + j * 16 + r16) * 32 + g * 8]);
#pragma unroll
    for (int i = 0; i < 4; ++i)
#pragma unroll
      for (int j = 0; j < 4; ++j)
        acc[i][j] = __builtin_amdgcn_mfma_f32_16x16x32_bf16(af[i], bfv[j], acc[i][j], 0, 0, 0);
    __syncthreads();
  }

  const int rr = g * 4;
#pragma unroll
  for (int i = 0; i < 4; ++i)
#pragma unroll
    for (int j = 0; j < 4; ++j)
#pragma unroll
      for (int q = 0; q < 4; ++q) {
        int mrow = m0 + wr * 64 + i * 16 + rr + q;
        int ncol = n0 + wc * 64 + j * 16 + r16;
        out[(size_t)mrow * N + ncol] = acc[i][j][q] + bias[ncol];
      }
}

// ---------------- attention with "+1" sink softmax, NO max subtraction ----------------
// CONSERVATIVE (r25): gload16 staging + dual __syncthreads (verified), B2 barrier
// RESTORED between P-store and PV (its removal was measured neutral in r8, so
// restoring is free and removes the same-wave-RAW risk), NO setprio (r24 suspect).
// Kept verified wins: swapped QK^T -> D[kv][q], exp2 domain, cvt_pk P-pack,
// ones-column row sums on the matrix pipe.
__global__ __launch_bounds__(256, 4) void k_attn(
    const unsigned short* __restrict__ Qh, const unsigned short* __restrict__ Kh,
    const unsigned short* __restrict__ Vt, unsigned short* __restrict__ X) {
  __shared__ unsigned short Kl[64 * 64];   // [kv][hd], chunk-swizzled
  __shared__ unsigned short Vl[64 * 64];   // [hd][kv], chunk-swizzled
  __shared__ unsigned short Pl[128 * 64];  // [q][kv],  chunk-swizzled

  const int tid = threadIdx.x, wid = tid >> 6, lane = tid & 63;
  const int g = lane >> 4, r16 = lane & 15;
  const int bh = blockIdx.y, b_ = bh >> 4, h_ = bh & 15;
  const int q0 = blockIdx.x * 128;
  const unsigned short* Qp = Qh + ((size_t)bh * SEQ + q0) * HDIM;
  const unsigned short* Kp = Kh + (size_t)bh * SEQ * HDIM;
  const unsigned short* Vp = Vt + (size_t)bh * HDIM * SEQ;
  const int qw = wid * 32;

  bf16x8 qf[2][2];
#pragma unroll
  for (int fr = 0; fr < 2; ++fr)
#pragma unroll
    for (int ks = 0; ks < 2; ++ks)
      qf[fr][ks] = *reinterpret_cast<const bf16x8*>(
          Qp + (size_t)(qw + fr * 16 + r16) * HDIM + ks * 32 + g * 8);

  bf16x8 vones;
#pragma unroll
  for (int i = 0; i < 8; ++i) vones[i] = (r16 == 0) ? (short)0x3F80 : (short)0;

  const int slot0 = wid * 64 + lane, slot1 = (4 + wid) * 64 + lane;
  const int sr0 = slot0 >> 3, sc0 = (slot0 & 7) ^ (sr0 & 7);
  const int sr1 = slot1 >> 3, sc1 = (slot1 & 7) ^ (sr1 & 7);
  const unsigned short* Ks0 = Kp + (size_t)sr0 * HDIM + sc0 * 8;
  const unsigned short* Ks1 = Kp + (size_t)sr1 * HDIM + sc1 * 8;
  const unsigned short* Vs0 = Vp + (size_t)sr0 * SEQ + sc0 * 8;
  const unsigned short* Vs1 = Vp + (size_t)sr1 * SEQ + sc1 * 8;
  const int ld0 = wid * 512, ld1 = (4 + wid) * 512;

  f32x4 o[2][4], ol[2];
#pragma unroll
  for (int fr = 0; fr < 2; ++fr) {
#pragma unroll
    for (int hf = 0; hf < 4; ++hf) o[fr][hf] = f32x4{0.f, 0.f, 0.f, 0.f};
    ol[fr] = f32x4{0.f, 0.f, 0.f, 0.f};
  }

  for (int t = 0; t < SEQ / 64; ++t) {
    __syncthreads();  // WAR: all waves done reading tile t-1 from Kl/Vl and Pl
    {
      const size_t koff = (size_t)t * 64 * HDIM;
      const int voff = t * 64;
      gload16(Ks0 + koff, &Kl[ld0]);
      gload16(Ks1 + koff, &Kl[ld1]);
      gload16(Vs0 + voff, &Vl[ld0]);
      gload16(Vs1 + voff, &Vl[ld1]);
    }
    __syncthreads();  // RAW: drains vmcnt -> tile t visible to all waves

    f32x4 s_[2][4];
#pragma unroll
    for (int fr = 0; fr < 2; ++fr)
#pragma unroll
      for (int cf = 0; cf < 4; ++cf) s_[fr][cf] = f32x4{0.f, 0.f, 0.f, 0.f};
#pragma unroll
    for (int cf = 0; cf < 4; ++cf) {
      int krow = cf * 16 + r16;
#pragma unroll
      for (int ks = 0; ks < 2; ++ks) {
        bf16x8 kf = *reinterpret_cast<const bf16x8*>(
            &Kl[krow * 64 + (((ks * 4 + g) ^ (krow & 7)) << 3)]);
#pragma unroll
        for (int fr = 0; fr < 2; ++fr)
          s_[fr][cf] = __builtin_amdgcn_mfma_f32_16x16x32_bf16(kf, qf[fr][ks], s_[fr][cf], 0, 0, 0);
      }
    }

#pragma unroll
    for (int fr = 0; fr < 2; ++fr) {
      int prow = qw + fr * 16 + r16;
      int base = prow * 64, swz = prow & 7;
#pragma unroll
      for (int cf = 0; cf < 4; ++cf) {
        float p0 = ex2(s_[fr][cf][0]);
        float p1 = ex2(s_[fr][cf][1]);
        float p2 = ex2(s_[fr][cf][2]);
        float p3 = ex2(s_[fr][cf][3]);
        unsigned w0 = cvtpk(p0, p1);
        unsigned w1 = cvtpk(p2, p3);
        int off = base + (((cf * 2 + (g >> 1)) ^ swz) << 3) + (g & 1) * 4;
        *reinterpret_cast<u32x2*>(&Pl[off]) = u32x2{w0, w1};
      }
    }
    __syncthreads();  // B2 RESTORED: Pl writes visible before PV reads (conservative)

#pragma unroll
    for (int ks = 0; ks < 2; ++ks) {
      bf16x8 pf[2];
#pragma unroll
      for (int fr = 0; fr < 2; ++fr) {
        int prow = qw + fr * 16 + r16;
        pf[fr] = *reinterpret_cast<const bf16x8*>(
            &Pl[prow * 64 + (((ks * 4 + g) ^ (prow & 7)) << 3)]);
      }
#pragma unroll
      for (int hf = 0; hf < 4; ++hf) {
        int vrow = hf * 16 + r16;
        bf16x8 vf = *reinterpret_cast<const bf16x8*>(
            &Vl[vrow * 64 + (((ks * 4 + g) ^ (vrow & 7)) << 3)]);
#pragma unroll
        for (int fr = 0; fr < 2; ++fr)
          o[fr][hf] = __builtin_amdgcn_mfma_f32_16x16x32_bf16(pf[fr], vf, o[fr][hf], 0, 0, 0);
      }
#pragma unroll
      for (int fr = 0; fr < 2; ++fr)
        ol[fr] = __builtin_amdgcn_mfma_f32_16x16x32_bf16(pf[fr], vones, ol[fr], 0, 0, 0);
    }
  }

#pragma unroll
  for (int fr = 0; fr < 2; ++fr) {
#pragma unroll
    for (int q = 0; q < 4; ++q) {
      float lsum = __shfl(ol[fr][q], lane & 48, 64);
      float inv = 1.0f / (1.0f + lsum);
      int row = q0 + qw + fr * 16 + g * 4 + q;
      unsigned short* xp = X + (size_t)(b_ * SEQ + row) * DIM + h_ * 64;
#pragma unroll
      for (int hf = 0; hf < 4; ++hf) xp[hf * 16 + r16] = f2b(o[fr][hf][q] * inv);
    }
  }
}

extern "C" void kernel_launch(void* const* d_in, const int* in_sizes, int n_in,
                              void* d_out, int out_size, void* d_ws, size_t ws_size,
                              hipStream_t stream) {
  const float* q  = (const float*)d_in[0];
  const float* k  = (const float*)d_in[1];
  const float* v  = (const float*)d_in[2];
  const float* Wq = (const float*)d_in[3];
  const float* bq = (const float*)d_in[4];
  const float* Wk = (const float*)d_in[5];
  const float* bk = (const float*)d_in[6];
  const float* Wv = (const float*)d_in[7];
  const float* bv = (const float*)d_in[8];
  const float* Wf = (const float*)d_in[9];
  const float* bf = (const float*)d_in[10];

  char* ws = (char*)d_ws;
  unsigned short* Abuf = (unsigned short*)ws;                              // attn X (8192*1024 bf16)
  unsigned short* Wt3  = (unsigned short*)(ws + (size_t)16777216);         // 3 x 1024x1024 bf16
  unsigned short* Wtf  = Wt3 + (size_t)3 * DIM * DIM;                      // 256x1024 bf16
  unsigned short* Qh   = Wtf + (size_t)DOUT * DIM;
  unsigned short* Kh   = Qh + (size_t)MROWS * DIM;
  unsigned short* Vtb  = Kh + (size_t)MROWS * DIM;

  dim3 b256(256);
  dim3 tb(32, 8);

  const float qscale = 0.125f * 1.44269504088896f;  // 1/sqrt(64) * log2(e): S in log2 units

  k_tcvt3<<<dim3(32, 32, 3), tb, 0, stream>>>(Wq, Wk, Wv, Wt3, DIM, DIM);
  k_tcvt<<<dim3(8, 32), tb, 0, stream>>>(Wf, Wtf, DIM, DOUT);
  k_gemm3<<<dim3(64, 8, 3), b256, 0, stream>>>(q, k, v, Wt3, bq, bk, bv, Qh, Kh, Vtb, qscale);
  k_attn<<<dim3(16, 64), b256, 0, stream>>>(Qh, Kh, Vtb, Abuf);
  k_gemmf<<<dim3(64, 2), b256, 0, stream>>>(Abuf, Wtf, bf, (float*)d_out, DIM, DOUT);
}